// Round 2
// baseline (112.377 us; speedup 1.0000x reference)
//
#include <hip/hip_runtime.h>

// GEMV: out[o] = sum_i x[i] * W[o*N_IN + i] + b[o]
// x: (1, 147456) f32, W: (1000, 147456) f32, b: (1000,), out: (1, 1000) f32.
// Memory-bound on the W stream (~590 MB) -> floor ~94 us @ 6.3 TB/s.
//
// Flat decomposition: W = 36,864,000 float4, split into 2048 chunks of
// 18,000 float4 (exactly 8 blocks/CU on 256 CUs -> full occupancy, zero
// tail). A chunk (18,000 < 36,864 = row size) spans at most 2 rows: keep
// two accumulators split at the row boundary, store partials to ws, then a
// tiny deterministic reduction kernel sums 2-3 partials per row. No atomics.

#define N_IN      147456
#define N_CLASSES 1000
#define R_VEC     36864     // float4 per row
#define CHUNK     18000     // float4 per block chunk
#define NBLK      2048      // chunks total: NBLK*CHUNK == N_CLASSES*R_VEC

__global__ __launch_bounds__(256, 8) void gemv_flat(
    const float* __restrict__ x,
    const float* __restrict__ W,
    float* __restrict__ ws)   // ws[2*NBLK]: {rowA partial, rowA+1 partial}
{
    const int b = blockIdx.x;
    const int start = b * CHUNK;            // max 36,864,000 fits in int
    const int end   = start + CHUNK;
    const int rowA  = start / R_VEC;
    const int rowAbase  = rowA * R_VEC;
    const int boundary  = rowAbase + R_VEC; // first vec index of next row

    const float4* __restrict__ Wv = reinterpret_cast<const float4*>(W);
    const float4* __restrict__ xv = reinterpret_cast<const float4*>(x);

    float acc0 = 0.0f, acc1 = 0.0f;
    for (int i = start + (int)threadIdx.x; i < end; i += 256) {
        const bool first = (i < boundary);
        const int  xi    = i - (first ? rowAbase : boundary);
        float4 wv = Wv[i];
        float4 xx = xv[xi];
        float d = wv.x * xx.x + wv.y * xx.y + wv.z * xx.z + wv.w * xx.w;
        if (first) acc0 += d; else acc1 += d;
    }

    // 64-lane wave reductions
    #pragma unroll
    for (int off = 32; off > 0; off >>= 1) {
        acc0 += __shfl_down(acc0, off, 64);
        acc1 += __shfl_down(acc1, off, 64);
    }

    __shared__ float s0[4], s1[4];
    const int wid  = threadIdx.x >> 6;
    const int lane = threadIdx.x & 63;
    if (lane == 0) { s0[wid] = acc0; s1[wid] = acc1; }
    __syncthreads();

    if (threadIdx.x == 0) {
        ws[2 * b]     = s0[0] + s0[1] + s0[2] + s0[3];
        ws[2 * b + 1] = s1[0] + s1[1] + s1[2] + s1[3];
    }
}

__global__ __launch_bounds__(256) void reduce_rows(
    const float* __restrict__ ws,
    const float* __restrict__ bias,
    float* __restrict__ out)
{
    const int r = blockIdx.x * 256 + threadIdx.x;
    if (r >= N_CLASSES) return;
    // blocks overlapping row r: those containing vec r*R_VEC .. (r+1)*R_VEC-1
    const int bStart = (r * R_VEC) / CHUNK;               // fits int
    const int bEnd   = ((r + 1) * R_VEC - 1) / CHUNK;
    float s = 0.0f;
    for (int b = bStart; b <= bEnd; ++b) {
        const int rowA = (b * CHUNK) / R_VEC;
        s += (rowA == r) ? ws[2 * b] : ws[2 * b + 1];
    }
    out[r] = s + bias[r];
}

// Fallback (previous verified kernel) if ws is unexpectedly tiny.
__global__ __launch_bounds__(256) void gemv_rowblock(
    const float* __restrict__ x,
    const float* __restrict__ W,
    const float* __restrict__ b,
    float* __restrict__ out)
{
    const int o = blockIdx.x;
    if (o >= N_CLASSES) return;
    const float4* __restrict__ Wrow =
        reinterpret_cast<const float4*>(W + (size_t)o * N_IN);
    const float4* __restrict__ xv = reinterpret_cast<const float4*>(x);
    float acc = 0.0f;
    for (int i = threadIdx.x; i < N_IN / 4; i += 256) {
        float4 wv = Wrow[i];
        float4 xx = xv[i];
        acc += wv.x * xx.x + wv.y * xx.y + wv.z * xx.z + wv.w * xx.w;
    }
    #pragma unroll
    for (int off = 32; off > 0; off >>= 1) acc += __shfl_down(acc, off, 64);
    __shared__ float s[4];
    if ((threadIdx.x & 63) == 0) s[threadIdx.x >> 6] = acc;
    __syncthreads();
    if (threadIdx.x == 0) out[o] = s[0] + s[1] + s[2] + s[3] + b[o];
}

extern "C" void kernel_launch(void* const* d_in, const int* in_sizes, int n_in,
                              void* d_out, int out_size, void* d_ws, size_t ws_size,
                              hipStream_t stream) {
    const float* x = (const float*)d_in[0];
    const float* W = (const float*)d_in[1];
    const float* b = (const float*)d_in[2];
    float* out = (float*)d_out;

    if (ws_size >= 2 * NBLK * sizeof(float)) {
        float* ws = (float*)d_ws;
        gemv_flat<<<NBLK, 256, 0, stream>>>(x, W, ws);
        reduce_rows<<<(N_CLASSES + 255) / 256, 256, 0, stream>>>(ws, b, out);
    } else {
        gemv_rowblock<<<N_CLASSES, 256, 0, stream>>>(x, W, b, out);
    }
}

// Round 4
// 104.283 us; speedup vs baseline: 1.0776x; 1.0776x over previous
//
#include <hip/hip_runtime.h>

// GEMV: out[o] = sum_i x[i] * W[o*N_IN + i] + b[o]
// x: (1, 147456) f32 (576 KB, reused 1000x -> keep in L2),
// W: (1000, 147456) f32 (~590 MB, streamed once -> non-temporal),
// out: (1, 1000) f32. HBM floor ~ 590 MB / 6.5 TB/s ~ 91 us.
//
// R1: row-per-block          107.0 us (5.5 TB/s effective on W)
// R2: flat 8-blk/CU 2-kernel 112.4 us -> occupancy NOT the limiter; reverted.
// R3: nt-loads on W — compile error (builtin needs ext_vector_type, not
//     HIP_vector_type). R4: same plan, native vector types.

#define N_IN      147456
#define N_CLASSES 1000
#define R_VEC     (N_IN / 4)           // 36864 float4 per row
#define ITERS     (R_VEC / (256 * 4))  // 36 outer iterations, no tail

typedef float vf4 __attribute__((ext_vector_type(4)));

__global__ __launch_bounds__(256) void gemv_rowblock_nt(
    const float* __restrict__ x,
    const float* __restrict__ W,
    const float* __restrict__ b,
    float* __restrict__ out)
{
    const int o = blockIdx.x;
    if (o >= N_CLASSES) return;

    const vf4* __restrict__ Wrow =
        reinterpret_cast<const vf4*>(W + (size_t)o * N_IN);
    const vf4* __restrict__ xv = reinterpret_cast<const vf4*>(x);

    float acc0 = 0.0f, acc1 = 0.0f, acc2 = 0.0f, acc3 = 0.0f;
    int i = threadIdx.x;
    #pragma unroll 1
    for (int it = 0; it < ITERS; ++it, i += 1024) {
        // 4 independent W loads (non-temporal: evict-first, keep x in L2)
        vf4 w0 = __builtin_nontemporal_load(&Wrow[i]);
        vf4 w1 = __builtin_nontemporal_load(&Wrow[i + 256]);
        vf4 w2 = __builtin_nontemporal_load(&Wrow[i + 512]);
        vf4 w3 = __builtin_nontemporal_load(&Wrow[i + 768]);
        // x loads: normal (cached, L2-resident)
        vf4 x0 = xv[i];
        vf4 x1 = xv[i + 256];
        vf4 x2 = xv[i + 512];
        vf4 x3 = xv[i + 768];
        acc0 += w0.x * x0.x + w0.y * x0.y + w0.z * x0.z + w0.w * x0.w;
        acc1 += w1.x * x1.x + w1.y * x1.y + w1.z * x1.z + w1.w * x1.w;
        acc2 += w2.x * x2.x + w2.y * x2.y + w2.z * x2.z + w2.w * x2.w;
        acc3 += w3.x * x3.x + w3.y * x3.y + w3.z * x3.z + w3.w * x3.w;
    }
    float acc = (acc0 + acc1) + (acc2 + acc3);

    // 64-lane wave reduction
    #pragma unroll
    for (int off = 32; off > 0; off >>= 1)
        acc += __shfl_down(acc, off, 64);

    __shared__ float s[4];
    const int wid  = threadIdx.x >> 6;
    const int lane = threadIdx.x & 63;
    if (lane == 0) s[wid] = acc;
    __syncthreads();

    if (threadIdx.x == 0) {
        out[o] = s[0] + s[1] + s[2] + s[3] + b[o];
    }
}

extern "C" void kernel_launch(void* const* d_in, const int* in_sizes, int n_in,
                              void* d_out, int out_size, void* d_ws, size_t ws_size,
                              hipStream_t stream) {
    const float* x = (const float*)d_in[0];
    const float* W = (const float*)d_in[1];
    const float* b = (const float*)d_in[2];
    float* out = (float*)d_out;

    gemv_rowblock_nt<<<N_CLASSES, 256, 0, stream>>>(x, W, b, out);
}

// Round 5
// 91.460 us; speedup vs baseline: 1.2287x; 1.1402x over previous
//
#include <hip/hip_runtime.h>

// GEMV: out[o] = sum_i x[i] * W[o*N_IN + i] + b[o]
// x: (1, 147456) f32 (576 KB, reused 1000x), W: (1000, 147456) f32 (~590 MB,
// streamed once, non-temporal), out: (1, 1000) f32.
// HBM floor ~ 590 MB / 6.5 TB/s ~ 91 us.
//
// R1: row-per-block                 107.0 us
// R2: flat 8-blk/CU 2-kernel        112.4 us (occupancy/balance NOT limiter)
// R4: + nt W loads + 4x unroll      104.3 us (x-eviction minor)
// R5: 2 rows/block (grid=500): halve x load instrs + x cache traffic;
//     W-stream MLP unchanged. If flat -> pure-read HBM ceiling reached.

#define N_IN      147456
#define N_CLASSES 1000
#define R_VEC     (N_IN / 4)           // 36864 float4 per row
#define ITERS     (R_VEC / (256 * 4))  // 36 outer iterations, no tail

typedef float vf4 __attribute__((ext_vector_type(4)));

__global__ __launch_bounds__(256) void gemv_2row_nt(
    const float* __restrict__ x,
    const float* __restrict__ W,
    const float* __restrict__ b,
    float* __restrict__ out)
{
    const int p = blockIdx.x;          // row pair index, 0..499
    const int r0 = 2 * p;

    const vf4* __restrict__ W0 =
        reinterpret_cast<const vf4*>(W + (size_t)r0 * N_IN);
    const vf4* __restrict__ W1 =
        reinterpret_cast<const vf4*>(W + (size_t)(r0 + 1) * N_IN);
    const vf4* __restrict__ xv = reinterpret_cast<const vf4*>(x);

    float a00 = 0.f, a01 = 0.f, a02 = 0.f, a03 = 0.f;   // row r0
    float a10 = 0.f, a11 = 0.f, a12 = 0.f, a13 = 0.f;   // row r0+1
    int i = threadIdx.x;
    #pragma unroll 1
    for (int it = 0; it < ITERS; ++it, i += 1024) {
        // shared x loads (cached)
        vf4 x0 = xv[i];
        vf4 x1 = xv[i + 256];
        vf4 x2 = xv[i + 512];
        vf4 x3 = xv[i + 768];
        // row 0 W loads (non-temporal streaming)
        vf4 u0 = __builtin_nontemporal_load(&W0[i]);
        vf4 u1 = __builtin_nontemporal_load(&W0[i + 256]);
        vf4 u2 = __builtin_nontemporal_load(&W0[i + 512]);
        vf4 u3 = __builtin_nontemporal_load(&W0[i + 768]);
        // row 1 W loads
        vf4 v0 = __builtin_nontemporal_load(&W1[i]);
        vf4 v1 = __builtin_nontemporal_load(&W1[i + 256]);
        vf4 v2 = __builtin_nontemporal_load(&W1[i + 512]);
        vf4 v3 = __builtin_nontemporal_load(&W1[i + 768]);

        a00 += u0.x * x0.x + u0.y * x0.y + u0.z * x0.z + u0.w * x0.w;
        a01 += u1.x * x1.x + u1.y * x1.y + u1.z * x1.z + u1.w * x1.w;
        a02 += u2.x * x2.x + u2.y * x2.y + u2.z * x2.z + u2.w * x2.w;
        a03 += u3.x * x3.x + u3.y * x3.y + u3.z * x3.z + u3.w * x3.w;
        a10 += v0.x * x0.x + v0.y * x0.y + v0.z * x0.z + v0.w * x0.w;
        a11 += v1.x * x1.x + v1.y * x1.y + v1.z * x1.z + v1.w * x1.w;
        a12 += v2.x * x2.x + v2.y * x2.y + v2.z * x2.z + v2.w * x2.w;
        a13 += v3.x * x3.x + v3.y * x3.y + v3.z * x3.z + v3.w * x3.w;
    }
    float accA = (a00 + a01) + (a02 + a03);
    float accB = (a10 + a11) + (a12 + a13);

    // 64-lane wave reductions
    #pragma unroll
    for (int off = 32; off > 0; off >>= 1) {
        accA += __shfl_down(accA, off, 64);
        accB += __shfl_down(accB, off, 64);
    }

    __shared__ float sA[4], sB[4];
    const int wid  = threadIdx.x >> 6;
    const int lane = threadIdx.x & 63;
    if (lane == 0) { sA[wid] = accA; sB[wid] = accB; }
    __syncthreads();

    if (threadIdx.x == 0) {
        out[r0]     = sA[0] + sA[1] + sA[2] + sA[3] + b[r0];
        out[r0 + 1] = sB[0] + sB[1] + sB[2] + sB[3] + b[r0 + 1];
    }
}

extern "C" void kernel_launch(void* const* d_in, const int* in_sizes, int n_in,
                              void* d_out, int out_size, void* d_ws, size_t ws_size,
                              hipStream_t stream) {
    const float* x = (const float*)d_in[0];
    const float* W = (const float*)d_in[1];
    const float* b = (const float*)d_in[2];
    float* out = (float*)d_out;

    gemv_2row_nt<<<N_CLASSES / 2, 256, 0, stream>>>(x, W, b, out);
}